// Round 10
// baseline (145.184 us; speedup 1.0000x reference)
//
#include <hip/hip_runtime.h>
#include <stdint.h>

// out = dequant( int8(lhs*ls) @ int8(rhs*rs) ) / (ls*rs), 4096^3, fp32 in/out.
// ls = 127 / max(amax|lhs|, 1e-12). Int core is bit-exact vs numpy (RNE quant).
//
// Workspace: [0,16Mi) qA int8 MxK ; [16Mi,32Mi) qBT int8 NxK ; then 2x u32 amax bits.
//
// GEMM v9: FAT WAVES, register-feasible. v8's counters showed the CU-shared
// LDS pipe is the binding resource: 8 thin waves (128x64) read 192 KB +
// stage 64 KB = 256 KB/window (~2000-2900 cyc) > MFMA window (2344 cyc).
// Read bytes scale as sum(Wm+Wn)*BK: 4 waves of 128x128 cut reads 33% ->
// LDS ~1536-2000 cyc < MFMA 2344 -> MFMA-bound for the first time.
// Register feasibility (v4/v5's killer) comes from v8's discovery: int32x16
// accumulators go to AGPRs (v8: VGPR_Count=92 with 128 acc regs). Here
// acc[4][4] = 256 AGPRs at 1 wave/SIMD (launch_bounds(256,1), 512 unified);
// VGPR side is just frags+addressing (~100). Everything else is the v6/v8
// proven skeleton: BK=128, double-buffered LDS (2 x 32 KiB x 2 = 128 KiB),
// prefetch-1, per window {stage next tile; compute cur (ks-interleaved reads
// + MFMAs); vmcnt(0) on window-old loads; s_barrier}; same LDS swizzle, same
// verified 32x32 fragment and C/D layouts (absmax 0.0 in v8).

#define NROW 4096
#define NELEM (4096 * 4096)

typedef __attribute__((ext_vector_type(4))) int int32x4;
typedef __attribute__((ext_vector_type(16))) int int32x16;
typedef const __attribute__((address_space(1))) int8_t* gptr1_t;
typedef __attribute__((address_space(3))) int8_t* lptr3_t;

__global__ void absmax_both_kernel(const float* __restrict__ lhs,
                                   const float* __restrict__ rhs,
                                   unsigned* __restrict__ amax) {
    __shared__ float red[4];
    const int t = blockIdx.x & 1;
    const float4* x4 = (const float4*)(t ? rhs : lhs);
    const int bid = blockIdx.x >> 1;
    const int stride = (gridDim.x >> 1) * blockDim.x;  // 262144
    int i = bid * blockDim.x + threadIdx.x;
    float m0 = 0.0f, m1 = 0.0f, m2 = 0.0f, m3 = 0.0f;
    for (; i + 3 * stride < NELEM / 4; i += 4 * stride) {
        float4 a = x4[i];
        float4 b = x4[i + stride];
        float4 c = x4[i + 2 * stride];
        float4 d = x4[i + 3 * stride];
        m0 = fmaxf(m0, fmaxf(fmaxf(fabsf(a.x), fabsf(a.y)),
                             fmaxf(fabsf(a.z), fabsf(a.w))));
        m1 = fmaxf(m1, fmaxf(fmaxf(fabsf(b.x), fabsf(b.y)),
                             fmaxf(fabsf(b.z), fabsf(b.w))));
        m2 = fmaxf(m2, fmaxf(fmaxf(fabsf(c.x), fabsf(c.y)),
                             fmaxf(fabsf(c.z), fabsf(c.w))));
        m3 = fmaxf(m3, fmaxf(fmaxf(fabsf(d.x), fabsf(d.y)),
                             fmaxf(fabsf(d.z), fabsf(d.w))));
    }
    for (; i < NELEM / 4; i += stride) {
        float4 a = x4[i];
        m0 = fmaxf(m0, fmaxf(fmaxf(fabsf(a.x), fabsf(a.y)),
                             fmaxf(fabsf(a.z), fabsf(a.w))));
    }
    float m = fmaxf(fmaxf(m0, m1), fmaxf(m2, m3));
    for (int off = 32; off > 0; off >>= 1)
        m = fmaxf(m, __shfl_down(m, off, 64));
    const int lane = threadIdx.x & 63, wave = threadIdx.x >> 6;
    if (lane == 0) red[wave] = m;
    __syncthreads();
    if (threadIdx.x == 0) {
        float b = fmaxf(fmaxf(red[0], red[1]), fmaxf(red[2], red[3]));
        atomicMax(amax + t, __float_as_uint(b));  // |x|>=0: bits monotone as uint
    }
}

__device__ __forceinline__ int q8(float v, float s) {
    int r = __float2int_rn(v * s);  // RNE, matches jnp.round
    r = r < -127 ? -127 : r;
    r = r > 127 ? 127 : r;
    return r;
}

__global__ void quant_kernel(const float* __restrict__ lhs,
                             const float* __restrict__ rhs,
                             int8_t* __restrict__ qA, int8_t* __restrict__ qT,
                             const unsigned* __restrict__ amax) {
    __shared__ int8_t sm[64][68];
    if (blockIdx.x < 16384) {
        const float s = 127.0f / fmaxf(__uint_as_float(amax[0]), 1e-12f);
        const int i = blockIdx.x * blockDim.x + threadIdx.x;
        float4 v = ((const float4*)lhs)[i];
        int b0 = q8(v.x, s), b1 = q8(v.y, s), b2 = q8(v.z, s), b3 = q8(v.w, s);
        ((int*)qA)[i] = (b0 & 0xff) | ((b1 & 0xff) << 8) | ((b2 & 0xff) << 16)
                      | ((b3 & 0xff) << 24);
    } else {
        const float s = 127.0f / fmaxf(__uint_as_float(amax[1]), 1e-12f);
        const int b = blockIdx.x - 16384;
        const int n0 = (b & 63) * 64, k0 = (b >> 6) * 64;
        const int rl = threadIdx.x >> 4;   // k row within 16-row slab
        const int nq = threadIdx.x & 15;   // float4 column
        for (int r = 0; r < 4; ++r) {
            const int kl = r * 16 + rl;
            float4 v = *(const float4*)(rhs + (size_t)(k0 + kl) * NROW + n0 + nq * 4);
            sm[nq * 4 + 0][kl] = (int8_t)q8(v.x, s);
            sm[nq * 4 + 1][kl] = (int8_t)q8(v.y, s);
            sm[nq * 4 + 2][kl] = (int8_t)q8(v.z, s);
            sm[nq * 4 + 3][kl] = (int8_t)q8(v.w, s);
        }
        __syncthreads();
        const int nl = threadIdx.x >> 2;
        const int kq = threadIdx.x & 3;
        int4 w;
        w.x = *(const int*)&sm[nl][kq * 16 + 0];
        w.y = *(const int*)&sm[nl][kq * 16 + 4];
        w.z = *(const int*)&sm[nl][kq * 16 + 8];
        w.w = *(const int*)&sm[nl][kq * 16 + 12];
        *(int4*)(qT + (size_t)(n0 + nl) * NROW + k0 + kq * 16) = w;
    }
}

// 256x256 tile, 4 waves (2Mx2N of 128x128 = 4x4 of 32x32), BK=128, double-
// buffered LDS. Window w: [stage tile w+1 -> slot (w+1)&1 (16 gload_lds/thr);
// compute slot w&1 (4 ks x {8 ds_read_b128 + 16 mfma_i32_32x32x32_i8});
// vmcnt(0) (loads a window old); s_barrier]. WAR safety: slot (w+1)&1 was
// read in window w-1; those reads complete before w-1's MFMAs (lgkm), which
// complete before w-1's barrier; the stage writes issue after that barrier.
__global__ __launch_bounds__(256, 1) void gemm_i8_kernel(
    const int8_t* __restrict__ qA, const int8_t* __restrict__ qBT,
    float* __restrict__ out, const unsigned* __restrict__ amax) {
    __shared__ __align__(16) int8_t sA[2][256 * 128];
    __shared__ __align__(16) int8_t sB[2][256 * 128];

    const int tid = threadIdx.x;
    const int lane = tid & 63;
    const int wave = tid >> 6;      // 0..3
    const int wm = wave >> 1;       // 0..1 : 128-row sub-tile
    const int wn = wave & 1;        // 0..1 : 128-col sub-tile

    // XCD-aware bijective swizzle (grid 256, 256%8==0): XCD k gets swz ids
    // [32k,32k+32) -> 2 contiguous M-rows: A-panels L2-resident per XCD.
    const int bid = blockIdx.y * 16 + blockIdx.x;
    const int swz = (bid & 7) * 32 + (bid >> 3);
    const int m0 = (swz >> 4) * 256, n0 = (swz & 15) * 256;

    const int rl = lane & 31;       // row within a 32-row MFMA tile
    const int hi = lane >> 5;       // k-half selector (16 B granule)

    // Frag read offsets (v8-verified). Global quad for k-slice ks:
    // g = 2*ks + hi; LDS pos = (g + row) & 7. Row steps of 32 (mt/nt) are
    // 0 mod 8 -> pos invariant; they fold into the ds_read immediate (+4096).
    const int rowA = wm * 128 + rl;
    const int rowB = wn * 128 + rl;
    int aoff4[4], boff4[4];
#pragma unroll
    for (int ks = 0; ks < 4; ++ks) {
        aoff4[ks] = rowA * 128 + (((2 * ks + hi + rowA) & 7) << 4);
        boff4[ks] = rowB * 128 + (((2 * ks + hi + rowB) & 7) << 4);
    }

    // Staging: 2048 16B-chunks per tensor per K-tile (256 rows x 8 quads),
    // 8 per thread (chunk c = tid + j*256). Linear LDS dst c*16 = tid*16 +
    // j*4096. Global source quad inverse-swizzled: row = c>>3 = (tid>>3)+j*32,
    // G = ((c&7) - row) & 7 = ((tid&7) - (tid>>3)) & 7 -- j-independent
    // (256 == 0 mod 8, 32 == 0 mod 8), so one pointer + j*32*NROW immediates.
    const int rowS = tid >> 3;
    const int G = ((tid & 7) - (rowS & 7)) & 7;
    const gptr1_t pA = (gptr1_t)(qA + (size_t)(m0 + rowS) * NROW + G * 16);
    const gptr1_t pB = (gptr1_t)(qBT + (size_t)(n0 + rowS) * NROW + G * 16);
    int8_t* sAf = &sA[0][0];
    int8_t* sBf = &sB[0][0];
    const int dst0 = tid * 16;

    auto stage = [&](int slot, int kb) {
#pragma unroll
        for (int j = 0; j < 8; ++j) {
            __builtin_amdgcn_global_load_lds(
                pA + kb + (size_t)j * 32 * NROW,
                (lptr3_t)(sAf + slot * 32768 + dst0 + j * 4096), 16, 0, 0);
            __builtin_amdgcn_global_load_lds(
                pB + kb + (size_t)j * 32 * NROW,
                (lptr3_t)(sBf + slot * 32768 + dst0 + j * 4096), 16, 0, 0);
        }
    };

    int32x16 acc[4][4];
#pragma unroll
    for (int mt = 0; mt < 4; ++mt)
#pragma unroll
        for (int nt = 0; nt < 4; ++nt) acc[mt][nt] = (int32x16)(0);

    auto compute = [&](const int8_t* a, const int8_t* b) {
#pragma unroll
        for (int ks = 0; ks < 4; ++ks) {
            int32x4 af[4], bf[4];
#pragma unroll
            for (int mt = 0; mt < 4; ++mt)
                af[mt] = *(const int32x4*)(a + aoff4[ks] + mt * 4096);
#pragma unroll
            for (int nt = 0; nt < 4; ++nt)
                bf[nt] = *(const int32x4*)(b + boff4[ks] + nt * 4096);
            __builtin_amdgcn_s_setprio(1);
#pragma unroll
            for (int mt = 0; mt < 4; ++mt)
#pragma unroll
                for (int nt = 0; nt < 4; ++nt)
                    acc[mt][nt] = __builtin_amdgcn_mfma_i32_32x32x32_i8(
                        af[mt], bf[nt], acc[mt][nt], 0, 0, 0);
            __builtin_amdgcn_s_setprio(0);
        }
    };

    // Prologue: stage tile 0 into slot 0; drain; barrier.
    stage(0, 0);
    asm volatile("s_waitcnt vmcnt(0)" ::: "memory");
    __builtin_amdgcn_sched_barrier(0);
    __builtin_amdgcn_s_barrier();
    __builtin_amdgcn_sched_barrier(0);

    // 32 K-tiles of 128. Windows 0..30 stage the next tile; window 31 below.
#pragma unroll 1
    for (int w = 0; w < 31; ++w) {
        stage((w + 1) & 1, (w + 1) * 128);
        compute(sAf + (w & 1) * 32768, sBf + (w & 1) * 32768);
        asm volatile("s_waitcnt vmcnt(0)" ::: "memory");
        __builtin_amdgcn_sched_barrier(0);
        __builtin_amdgcn_s_barrier();
        __builtin_amdgcn_sched_barrier(0);
    }
    compute(sAf + 32768, sBf + 32768);  // tile 31, slot 1

    // Epilogue: dequant + store. 32x32 C/D layout: col = lane&31,
    // row = (reg&3) + 8*(reg>>2) + 4*(lane>>5).
    const float ls = 127.0f / fmaxf(__uint_as_float(amax[0]), 1e-12f);
    const float rs = 127.0f / fmaxf(__uint_as_float(amax[1]), 1e-12f);
    const float inv = 1.0f / (ls * rs);
#pragma unroll
    for (int mt = 0; mt < 4; ++mt)
#pragma unroll
        for (int nt = 0; nt < 4; ++nt)
#pragma unroll
            for (int reg = 0; reg < 16; ++reg) {
                const int row = m0 + wm * 128 + mt * 32 + (reg & 3) +
                                8 * (reg >> 2) + 4 * hi;
                const int col = n0 + wn * 128 + nt * 32 + rl;
                out[(size_t)row * NROW + col] = (float)acc[mt][nt][reg] * inv;
            }
}

extern "C" void kernel_launch(void* const* d_in, const int* in_sizes, int n_in,
                              void* d_out, int out_size, void* d_ws,
                              size_t ws_size, hipStream_t stream) {
    const float* lhs = (const float*)d_in[0];
    const float* rhs = (const float*)d_in[1];
    float* out = (float*)d_out;

    int8_t* qA = (int8_t*)d_ws;
    int8_t* qBT = qA + (size_t)16 * 1024 * 1024;
    unsigned* amax = (unsigned*)(qBT + (size_t)16 * 1024 * 1024);

    hipMemsetAsync(amax, 0, 8, stream);
    absmax_both_kernel<<<2048, 256, 0, stream>>>(lhs, rhs, amax);
    quant_kernel<<<16384 + 4096, 256, 0, stream>>>(lhs, rhs, qA, qBT, amax);
    gemm_i8_kernel<<<dim3(16, 16), 256, 0, stream>>>(qA, qBT, out, amax);
}

// Round 11
// 142.440 us; speedup vs baseline: 1.0193x; 1.0193x over previous
//
#include <hip/hip_runtime.h>
#include <stdint.h>

// out = dequant( int8(lhs*ls) @ int8(rhs*rs) ) / (ls*rs), 4096^3, fp32 in/out.
// ls = 127 / max(amax|lhs|, 1e-12). Int core is bit-exact vs numpy (RNE quant).
//
// Workspace: [0,16Mi) qA frag-layout ; [16Mi,32Mi) qBT frag-layout ; 2x u32 amax.
//
// GEMM v10: NO-LDS fragment-direct GEMM. Seven LDS-staged structures (v1-v9:
// thin/fat waves, BK 64/128, 1/4 phases, prefetch 0/1/2, occupancy 10-37%)
// all landed 83-95 us at ~34% MfmaUtil -- the stage+barrier+ds_read paradigm
// itself is the wall (m233: MFMA-only 86% of peak, full staged loop 24%,
// removing single elements doesn't help). Since WE write qA/qBT, the quant
// kernels emit them in MFMA-FRAGMENT ORDER: chunk ((tile*128+ks)*64+lane)*16
// = lane's 16 bytes of one 32x32x32 fragment. The GEMM then loads fragments
// with single coalesced global_load_dwordx4 (offset lane*16) straight into
// VGPRs: no LDS, no barriers, no waitcnt asm, no swizzle. Reuse via L1/L2/L3
// (A shared by 4 waves in-block, L2-resident per XCD; 32 MB total << L3).
// Waves free-run; ks-slice software pipeline (load s+1 under 8 MFMAs of s)
// + 2 waves/SIMD hide VMEM latency. acc[4][2] int32x16 -> 128 AGPRs (v8:
// VGPR_Count 92 at this exact acc shape); frag dbuf 48 VGPR.
//
// Fragment layouts (verified in v8/v9, absmax 0.0):
//   A: byte ((mt_g*128+ks_g)*64 + l)*16 + j = qA8[mt_g*32+(l&31)][ks_g*32+(l>>5)*16+j]
//   B: byte ((nt_g*128+ks_g)*64 + l)*16 + j = qBT8[nt_g*32+(l&31)][ks_g*32+(l>>5)*16+j]
//   C/D: col = lane&31, row = (reg&3) + 8*(reg>>2) + 4*(lane>>5).

#define NROW 4096
#define NELEM (4096 * 4096)

typedef __attribute__((ext_vector_type(4))) int int32x4;
typedef __attribute__((ext_vector_type(16))) int int32x16;

__global__ void absmax_both_kernel(const float* __restrict__ lhs,
                                   const float* __restrict__ rhs,
                                   unsigned* __restrict__ amax) {
    __shared__ float red[4];
    const int t = blockIdx.x & 1;
    const float4* x4 = (const float4*)(t ? rhs : lhs);
    const int bid = blockIdx.x >> 1;
    const int stride = (gridDim.x >> 1) * blockDim.x;  // 262144
    int i = bid * blockDim.x + threadIdx.x;
    float m0 = 0.0f, m1 = 0.0f, m2 = 0.0f, m3 = 0.0f;
    for (; i + 3 * stride < NELEM / 4; i += 4 * stride) {
        float4 a = x4[i];
        float4 b = x4[i + stride];
        float4 c = x4[i + 2 * stride];
        float4 d = x4[i + 3 * stride];
        m0 = fmaxf(m0, fmaxf(fmaxf(fabsf(a.x), fabsf(a.y)),
                             fmaxf(fabsf(a.z), fabsf(a.w))));
        m1 = fmaxf(m1, fmaxf(fmaxf(fabsf(b.x), fabsf(b.y)),
                             fmaxf(fabsf(b.z), fabsf(b.w))));
        m2 = fmaxf(m2, fmaxf(fmaxf(fabsf(c.x), fabsf(c.y)),
                             fmaxf(fabsf(c.z), fabsf(c.w))));
        m3 = fmaxf(m3, fmaxf(fmaxf(fabsf(d.x), fabsf(d.y)),
                             fmaxf(fabsf(d.z), fabsf(d.w))));
    }
    for (; i < NELEM / 4; i += stride) {
        float4 a = x4[i];
        m0 = fmaxf(m0, fmaxf(fmaxf(fabsf(a.x), fabsf(a.y)),
                             fmaxf(fabsf(a.z), fabsf(a.w))));
    }
    float m = fmaxf(fmaxf(m0, m1), fmaxf(m2, m3));
    for (int off = 32; off > 0; off >>= 1)
        m = fmaxf(m, __shfl_down(m, off, 64));
    const int lane = threadIdx.x & 63, wave = threadIdx.x >> 6;
    if (lane == 0) red[wave] = m;
    __syncthreads();
    if (threadIdx.x == 0) {
        float b = fmaxf(fmaxf(red[0], red[1]), fmaxf(red[2], red[3]));
        atomicMax(amax + t, __float_as_uint(b));  // |x|>=0: bits monotone as uint
    }
}

__device__ __forceinline__ int q8(float v, float s) {
    int r = __float2int_rn(v * s);  // RNE, matches jnp.round
    r = r < -127 ? -127 : r;
    r = r > 127 ? 127 : r;
    return r;
}

__device__ __forceinline__ int pack4(float a, float b, float c, float d,
                                     float s) {
    return (q8(a, s) & 0xff) | ((q8(b, s) & 0xff) << 8) |
           ((q8(c, s) & 0xff) << 16) | ((q8(d, s) & 0xff) << 24);
}

// Blocks [0,4096): A -> fragment layout. Thread t handles chunk
// c = blockIdx*256+t: l=c&63, ks_g=(c>>6)&127, mt_g=c>>13; reads 16 fp32 from
// lhs[mt_g*32+(l&31)][ks_g*32+(l>>5)*16 ..], writes 16 int8 to qA+c*16
// (fully contiguous stores; reads pull full 64B lines, L1 merges halves).
// Blocks [4096,8192): B -> LDS 64x64 transpose (verified), frag-order output.
__global__ void quant_kernel(const float* __restrict__ lhs,
                             const float* __restrict__ rhs,
                             int8_t* __restrict__ qA, int8_t* __restrict__ qT,
                             const unsigned* __restrict__ amax) {
    __shared__ int8_t sm[64][68];
    if (blockIdx.x < 4096) {
        const float s = 127.0f / fmaxf(__uint_as_float(amax[0]), 1e-12f);
        const int c = blockIdx.x * 256 + threadIdx.x;
        const int l = c & 63;
        const int ks_g = (c >> 6) & 127;
        const int mt_g = c >> 13;
        const int row = mt_g * 32 + (l & 31);
        const int kb = ks_g * 32 + (l >> 5) * 16;
        const float4* src = (const float4*)(lhs + (size_t)row * NROW + kb);
        float4 v0 = src[0], v1 = src[1], v2 = src[2], v3 = src[3];
        int4 w;
        w.x = pack4(v0.x, v0.y, v0.z, v0.w, s);
        w.y = pack4(v1.x, v1.y, v1.z, v1.w, s);
        w.z = pack4(v2.x, v2.y, v2.z, v2.w, s);
        w.w = pack4(v3.x, v3.y, v3.z, v3.w, s);
        *(int4*)(qA + (size_t)c * 16) = w;
    } else {
        const float s = 127.0f / fmaxf(__uint_as_float(amax[1]), 1e-12f);
        const int b = blockIdx.x - 4096;
        const int n0 = (b & 63) * 64, k0 = (b >> 6) * 64;
        const int rl = threadIdx.x >> 4;   // k row within 16-row slab
        const int nq = threadIdx.x & 15;   // float4 column
        for (int r = 0; r < 4; ++r) {
            const int kl = r * 16 + rl;
            float4 v = *(const float4*)(rhs + (size_t)(k0 + kl) * NROW + n0 + nq * 4);
            sm[nq * 4 + 0][kl] = (int8_t)q8(v.x, s);
            sm[nq * 4 + 1][kl] = (int8_t)q8(v.y, s);
            sm[nq * 4 + 2][kl] = (int8_t)q8(v.z, s);
            sm[nq * 4 + 3][kl] = (int8_t)q8(v.w, s);
        }
        __syncthreads();
        // Frag-order store: tile = 2 nt x 2 ks x 64 lanes = 256 chunks.
        const int nt_l = threadIdx.x >> 7;        // 0..1
        const int ks_l = (threadIdx.x >> 6) & 1;  // 0..1
        const int l = threadIdx.x & 63;
        const int n_loc = nt_l * 32 + (l & 31);
        const int k_loc = ks_l * 32 + (l >> 5) * 16;
        int4 w;  // 4x b32 reads (68B rows: 16B-unaligned, 4B-aligned; stride
                 // 17 words -> conflict-free)
        w.x = *(const int*)&sm[n_loc][k_loc + 0];
        w.y = *(const int*)&sm[n_loc][k_loc + 4];
        w.z = *(const int*)&sm[n_loc][k_loc + 8];
        w.w = *(const int*)&sm[n_loc][k_loc + 12];
        const int nt_g = (b & 63) * 2 + nt_l;
        const int ks_g = (b >> 6) * 2 + ks_l;
        *(int4*)(qT + (((size_t)nt_g * 128 + ks_g) * 64 + l) * 16) = w;
    }
}

// 256x256 tile, 8 waves (2Mx4N of 128x64 = 4x2 of 32x32), no LDS, no
// barriers. Flat loop over 128 k-slices: load slice s+1 frags (6 coalesced
// global_load_dwordx4) while MFMAing slice s (8 mfma_i32_32x32x32_i8).
// F0/F1 register alternation via 2-unroll (no dynamic indexing).
__global__ __launch_bounds__(512, 2) void gemm_i8_kernel(
    const int8_t* __restrict__ qA, const int8_t* __restrict__ qBT,
    float* __restrict__ out, const unsigned* __restrict__ amax) {
    const int tid = threadIdx.x;
    const int lane = tid & 63;
    const int wave = tid >> 6;      // 0..7
    const int wm = wave >> 2;       // 0..1 : 128-row sub-tile
    const int wn = wave & 3;        // 0..3 : 64-col sub-tile

    // XCD-aware bijective swizzle (grid 256, 256%8==0): XCD k gets swz ids
    // [32k,32k+32) -> 2 contiguous M-rows: A frags L2-resident per XCD.
    const int bid = blockIdx.y * 16 + blockIdx.x;
    const int swz = (bid & 7) * 32 + (bid >> 3);
    const int m0 = (swz >> 4) * 256, n0 = (swz & 15) * 256;

    const int rl = lane & 31;       // row within a 32-row MFMA tile
    const int hi = lane >> 5;       // k-half selector

    // Per-lane fragment base pointers. Frag (tile_g, ks_g) at
    // ((tile_g*128 + ks_g)*64 + lane)*16; mt step = 128*1024 B, ks step = 1024 B.
    const int8_t* pa = qA + ((size_t)(m0 / 32 + wm * 4) * 128 + 0) * 1024 + lane * 16;
    const int8_t* pb = qBT + ((size_t)(n0 / 32 + wn * 2) * 128 + 0) * 1024 + lane * 16;

    int32x16 acc[4][2];
#pragma unroll
    for (int mt = 0; mt < 4; ++mt)
#pragma unroll
        for (int nt = 0; nt < 2; ++nt) acc[mt][nt] = (int32x16)(0);

    int32x4 a0[4], b0[2], a1[4], b1[2];

#define LOADF(A, B, S)                                                        \
    {                                                                         \
        const int8_t* ap = pa + (S)*1024;                                     \
        const int8_t* bp = pb + (S)*1024;                                     \
        A[0] = *(const int32x4*)(ap);                                         \
        A[1] = *(const int32x4*)(ap + 131072);                                \
        A[2] = *(const int32x4*)(ap + 262144);                                \
        A[3] = *(const int32x4*)(ap + 393216);                                \
        B[0] = *(const int32x4*)(bp);                                         \
        B[1] = *(const int32x4*)(bp + 131072);                                \
    }

#define MFMAF(A, B)                                                           \
    {                                                                         \
        __builtin_amdgcn_s_setprio(1);                                        \
        _Pragma("unroll") for (int mt = 0; mt < 4; ++mt)                      \
            _Pragma("unroll") for (int nt = 0; nt < 2; ++nt) acc[mt][nt] =    \
                __builtin_amdgcn_mfma_i32_32x32x32_i8(A[mt], B[nt],           \
                                                      acc[mt][nt], 0, 0, 0);  \
        __builtin_amdgcn_s_setprio(0);                                        \
    }

    LOADF(a0, b0, 0)
#pragma unroll 1
    for (int s = 0; s < 126; s += 2) {
        LOADF(a1, b1, s + 1)
        MFMAF(a0, b0)
        LOADF(a0, b0, s + 2)
        MFMAF(a1, b1)
    }
    LOADF(a1, b1, 127)
    MFMAF(a0, b0)  // slice 126
    MFMAF(a1, b1)  // slice 127

    // Epilogue: dequant + store. 32x32 C/D layout: col = lane&31,
    // row = (reg&3) + 8*(reg>>2) + 4*(lane>>5).
    const float ls = 127.0f / fmaxf(__uint_as_float(amax[0]), 1e-12f);
    const float rs = 127.0f / fmaxf(__uint_as_float(amax[1]), 1e-12f);
    const float inv = 1.0f / (ls * rs);
#pragma unroll
    for (int mt = 0; mt < 4; ++mt)
#pragma unroll
        for (int nt = 0; nt < 2; ++nt)
#pragma unroll
            for (int reg = 0; reg < 16; ++reg) {
                const int row = m0 + wm * 128 + mt * 32 + (reg & 3) +
                                8 * (reg >> 2) + 4 * hi;
                const int col = n0 + wn * 64 + nt * 32 + rl;
                out[(size_t)row * NROW + col] = (float)acc[mt][nt][reg] * inv;
            }
#undef LOADF
#undef MFMAF
}

extern "C" void kernel_launch(void* const* d_in, const int* in_sizes, int n_in,
                              void* d_out, int out_size, void* d_ws,
                              size_t ws_size, hipStream_t stream) {
    const float* lhs = (const float*)d_in[0];
    const float* rhs = (const float*)d_in[1];
    float* out = (float*)d_out;

    int8_t* qA = (int8_t*)d_ws;
    int8_t* qBT = qA + (size_t)16 * 1024 * 1024;
    unsigned* amax = (unsigned*)(qBT + (size_t)16 * 1024 * 1024);

    hipMemsetAsync(amax, 0, 8, stream);
    absmax_both_kernel<<<2048, 256, 0, stream>>>(lhs, rhs, amax);
    quant_kernel<<<4096 + 4096, 256, 0, stream>>>(lhs, rhs, qA, qBT, amax);
    gemm_i8_kernel<<<dim3(16, 16), 512, 0, stream>>>(qA, qBT, out, amax);
}